// Round 1
// baseline (1976.375 us; speedup 1.0000x reference)
//
#include <hip/hip_runtime.h>

#define HID 128

typedef __bf16 bf16x8 __attribute__((ext_vector_type(8)));
typedef float f32x4 __attribute__((ext_vector_type(4)));

__device__ __forceinline__ unsigned short f2bf(float x) {
  unsigned int u = __builtin_bit_cast(unsigned int, x);
  u += 0x7FFFu + ((u >> 16) & 1u);
  return (unsigned short)(u >> 16);
}

__global__ void zero_int_kernel(int* __restrict__ p, int n) {
  int i = blockIdx.x * blockDim.x + threadIdx.x;
  if (i < n) p[i] = 0;
}

__global__ void degree_kernel(const int* __restrict__ dst, int* __restrict__ deg, int n) {
  int i = blockIdx.x * blockDim.x + threadIdx.x;
  if (i < n) atomicAdd(&deg[dst[i]], 1);
}

// single-block exclusive scan over deg[0..n) -> eoff[0..n]
__global__ void __launch_bounds__(1024) scan_kernel(const int* __restrict__ deg,
                                                    int* __restrict__ eoff, int n) {
  __shared__ int ssum[1024];
  int t = threadIdx.x;
  int chunk = (n + 1023) / 1024;
  int beg = t * chunk;
  int end = min(beg + chunk, n);
  int s = 0;
  for (int i = beg; i < end; ++i) s += deg[i];
  ssum[t] = s;
  __syncthreads();
  for (int off = 1; off < 1024; off <<= 1) {
    int v = (t >= off) ? ssum[t - off] : 0;
    __syncthreads();
    ssum[t] += v;
    __syncthreads();
  }
  int base = (t == 0) ? 0 : ssum[t - 1];
  for (int i = beg; i < end; ++i) { eoff[i] = base; base += deg[i]; }
  if (t == 1023) eoff[n] = base;
}

__global__ void copy_int_kernel(const int* __restrict__ src, int* __restrict__ dst, int n) {
  int i = blockIdx.x * blockDim.x + threadIdx.x;
  if (i < n) dst[i] = src[i];
}

__global__ void scatter_kernel(const int* __restrict__ edst, int* __restrict__ cursor,
                               int* __restrict__ esort, int n) {
  int i = blockIdx.x * blockDim.x + threadIdx.x;
  if (i < n) {
    int d = edst[i];
    int pos = atomicAdd(&cursor[d], 1);
    esort[pos] = i;
  }
}

// one block (128 thr) per node: h0[node][t] = relu(sum_bag fw*emb[id][t] + bias[t])
__global__ void __launch_bounds__(128) embed_kernel(const int* __restrict__ ids,
                                                    const int* __restrict__ offs,
                                                    const float* __restrict__ fw,
                                                    const float* __restrict__ emb,
                                                    const float* __restrict__ bias,
                                                    float* __restrict__ h) {
  int node = blockIdx.x;
  int t = threadIdx.x;
  int beg = offs[node], end = offs[node + 1];
  float acc = 0.f;
  for (int i = beg; i < end; ++i) {
    acc += fw[i] * emb[(long)ids[i] * HID + t];
  }
  acc += bias[t];
  h[(long)node * HID + t] = acc > 0.f ? acc : 0.f;
}

// one block (128 thr) per dst node: accumulate agg (ppi) and res (self) over CSR in-edges
__global__ void __launch_bounds__(128) aggregate_kernel(const float* __restrict__ h,
                                                        const int* __restrict__ eoff,
                                                        const int* __restrict__ esort,
                                                        const int* __restrict__ esrc,
                                                        const float* __restrict__ ppi,
                                                        const float* __restrict__ selfw,
                                                        float* __restrict__ agg,
                                                        float* __restrict__ res) {
  int node = blockIdx.x;
  int t = threadIdx.x;
  int beg = eoff[node], end = eoff[node + 1];
  float a = 0.f, r = 0.f;
  for (int j = beg; j < end; ++j) {
    int e = esort[j];
    int s = esrc[e];
    float v = h[(long)s * HID + t];
    a += ppi[e] * v;
    r += selfw[e] * v;
  }
  agg[(long)node * HID + t] = a;
  res[(long)node * HID + t] = r;
}

// hout[node][t] = relu(agg[node]@W + b)[t] + res[node][t] ; W cached in LDS (f32, exact)
__global__ void __launch_bounds__(256) update_kernel(const float* __restrict__ agg,
                                                     const float* __restrict__ res,
                                                     const float* __restrict__ W,
                                                     const float* __restrict__ b,
                                                     float* __restrict__ hout, int n_nodes) {
  __shared__ __align__(16) float sW[HID * HID];
  __shared__ float sx[2][HID];
  int t = threadIdx.x & (HID - 1);
  int sub = threadIdx.x >> 7;
  for (int i = threadIdx.x; i < HID * HID / 4; i += 256)
    ((float4*)sW)[i] = ((const float4*)W)[i];
  float bias = b[t];
  __syncthreads();
  for (int node0 = blockIdx.x * 2; node0 < n_nodes; node0 += gridDim.x * 2) {
    int node = node0 + sub;
    bool valid = node < n_nodes;
    if (valid) sx[sub][t] = agg[(long)node * HID + t];
    __syncthreads();
    if (valid) {
      float acc = 0.f;
#pragma unroll 16
      for (int k = 0; k < HID; ++k) acc += sx[sub][k] * sW[k * HID + t];
      float v = acc + bias;
      v = v > 0.f ? v : 0.f;
      hout[(long)node * HID + t] = v + res[(long)node * HID + t];
    }
    __syncthreads();
  }
}

// WoT[n][k] = bf16(Wo[k][n])
__global__ void transpose_wo_kernel(const float* __restrict__ Wo,
                                    unsigned short* __restrict__ WoT, int labels) {
  int idx = blockIdx.x * 256 + threadIdx.x;
  if (idx < labels * HID) {
    int n = idx >> 7, k = idx & (HID - 1);
    WoT[idx] = f2bf(Wo[(long)k * labels + n]);
  }
}

#define LDK 136  // padded LDS K-stride (shorts); 272B rows keep 16B alignment, break bank aliasing

// out[50000 x labels] = h @ Wo + bo, bf16 MFMA, f32 accumulate.
// block = 256 thr = 4 waves; block tile 64(M) x 80(N); full K=128 staged once.
__global__ void __launch_bounds__(256) out_gemm_kernel(const float* __restrict__ h,
                                                       const unsigned short* __restrict__ WoT,
                                                       const float* __restrict__ bo,
                                                       float* __restrict__ out,
                                                       int n_nodes, int labels) {
  __shared__ __align__(16) unsigned short sA[64 * LDK];
  __shared__ __align__(16) unsigned short sB[80 * LDK];
  int m0 = blockIdx.x * 64;
  int n0 = blockIdx.y * 80;
  int tid = threadIdx.x;

  // stage A: 64 rows x 128 cols of h, f32 -> bf16
  for (int i = tid; i < 64 * 32; i += 256) {
    int r = i >> 5, c4 = i & 31;
    int row = m0 + r;
    if (row >= n_nodes) row = n_nodes - 1;  // clamp: loads valid, stores bounded later
    float4 v = ((const float4*)(h + (long)row * HID))[c4];
    ushort4 bb;
    bb.x = f2bf(v.x); bb.y = f2bf(v.y); bb.z = f2bf(v.z); bb.w = f2bf(v.w);
    *(ushort4*)&sA[r * LDK + c4 * 4] = bb;
  }
  // stage B: 80 rows (n) x 128 cols (k) of WoT (already bf16)
  for (int i = tid; i < 80 * 32; i += 256) {
    int r = i >> 5, c4 = i & 31;
    ushort4 v = ((const ushort4*)(WoT + (long)(n0 + r) * HID))[c4];
    *(ushort4*)&sB[r * LDK + c4 * 4] = v;
  }
  __syncthreads();

  int wave = tid >> 6, lane = tid & 63;
  int lrow = lane & 15, quad = lane >> 4;
  f32x4 acc[5];
#pragma unroll
  for (int c = 0; c < 5; ++c) acc[c] = (f32x4){0.f, 0.f, 0.f, 0.f};

#pragma unroll
  for (int kk = 0; kk < 4; ++kk) {
    bf16x8 af = *(const bf16x8*)&sA[(wave * 16 + lrow) * LDK + kk * 32 + quad * 8];
#pragma unroll
    for (int c = 0; c < 5; ++c) {
      bf16x8 bf = *(const bf16x8*)&sB[(c * 16 + lrow) * LDK + kk * 32 + quad * 8];
      acc[c] = __builtin_amdgcn_mfma_f32_16x16x32_bf16(af, bf, acc[c], 0, 0, 0);
    }
  }

  // epilogue: D mapping col = lane&15, row = quad*4 + reg
#pragma unroll
  for (int c = 0; c < 5; ++c) {
    int n = n0 + c * 16 + lrow;
    float bias = bo[n];
#pragma unroll
    for (int r = 0; r < 4; ++r) {
      int m = m0 + wave * 16 + quad * 4 + r;
      if (m < n_nodes) out[(long)m * labels + n] = acc[c][r] + bias;
    }
  }
}

extern "C" void kernel_launch(void* const* d_in, const int* in_sizes, int n_in,
                              void* d_out, int out_size, void* d_ws, size_t ws_size,
                              hipStream_t stream) {
  const int* feat_ids = (const int*)d_in[0];
  const int* offsets = (const int*)d_in[1];
  const float* feat_w = (const float*)d_in[2];
  const int* esrc = (const int*)d_in[3];
  const int* edst = (const int*)d_in[4];
  const float* ppi = (const float*)d_in[5];
  const float* selfw = (const float*)d_in[6];
  const float* emb = (const float*)d_in[7];
  const float* ibias = (const float*)d_in[8];
  const float* W1 = (const float*)d_in[9];
  const float* b1 = (const float*)d_in[10];
  const float* W2 = (const float*)d_in[11];
  const float* b2 = (const float*)d_in[12];
  const float* Wo = (const float*)d_in[13];
  const float* bo = (const float*)d_in[14];
  float* out = (float*)d_out;

  int N = in_sizes[1] - 1;       // 50000
  int E = in_sizes[3];           // 1600000
  int LABELS = in_sizes[14];     // 2000

  char* ws = (char*)d_ws;
  size_t HN = (size_t)N * HID;
  float* h0 = (float*)ws;                    ws += HN * 4;
  float* agg = (float*)ws;                   ws += HN * 4;
  float* res = (float*)ws;                   ws += HN * 4;
  unsigned short* WoT = (unsigned short*)ws; ws += (size_t)LABELS * HID * 2;
  int* deg = (int*)ws;                       ws += (size_t)N * 4;
  int* eoff = (int*)ws;                      ws += (size_t)(N + 1) * 4;
  int* cursor = (int*)ws;                    ws += (size_t)N * 4;
  int* esort = (int*)ws;                     ws += (size_t)E * 4;

  // build dst-CSR (reused by both layers)
  zero_int_kernel<<<(N + 255) / 256, 256, 0, stream>>>(deg, N);
  degree_kernel<<<(E + 255) / 256, 256, 0, stream>>>(edst, deg, E);
  scan_kernel<<<1, 1024, 0, stream>>>(deg, eoff, N);
  copy_int_kernel<<<(N + 255) / 256, 256, 0, stream>>>(eoff, cursor, N);
  scatter_kernel<<<(E + 255) / 256, 256, 0, stream>>>(edst, cursor, esort, E);

  // input layer
  embed_kernel<<<N, HID, 0, stream>>>(feat_ids, offsets, feat_w, emb, ibias, h0);
  transpose_wo_kernel<<<(LABELS * HID + 255) / 256, 256, 0, stream>>>(Wo, WoT, LABELS);

  // GCN layer 1
  aggregate_kernel<<<N, HID, 0, stream>>>(h0, eoff, esort, esrc, ppi, selfw, agg, res);
  update_kernel<<<1024, 256, 0, stream>>>(agg, res, W1, b1, h0, N);
  // GCN layer 2
  aggregate_kernel<<<N, HID, 0, stream>>>(h0, eoff, esort, esrc, ppi, selfw, agg, res);
  update_kernel<<<1024, 256, 0, stream>>>(agg, res, W2, b2, h0, N);

  // output layer
  dim3 g((N + 63) / 64, LABELS / 80);
  out_gemm_kernel<<<g, 256, 0, stream>>>(h0, WoT, bo, out, N, LABELS);
}